// Round 13
// baseline (321.189 us; speedup 1.0000x reference)
//
#include <hip/hip_runtime.h>
#include <hip/hip_bf16.h>

#define NROWS 8192
typedef unsigned short u16;
typedef short bf16x8 __attribute__((ext_vector_type(8)));
typedef short bf16x4 __attribute__((ext_vector_type(4)));
typedef float f32x4 __attribute__((ext_vector_type(4)));

#if __has_builtin(__builtin_amdgcn_global_load_lds)
#define HAS_GLL 1
typedef __attribute__((address_space(3))) void lds_void;
typedef __attribute__((address_space(1))) const void glb_cvoid;
#else
#define HAS_GLL 0
#endif

__device__ __forceinline__ u16 f2b(float f) {   // fp32 -> bf16 RNE
    unsigned u = __float_as_uint(f);
    unsigned r = (u + 0x7fffu + ((u >> 16) & 1u)) >> 16;
    return (u16)r;
}
__device__ __forceinline__ float b2f(u16 v) {
    return __uint_as_float(((unsigned)v) << 16);
}

template<int MODE> __device__ __forceinline__ float actf(float v) {
    if constexpr (MODE == 1) return fmaxf(v, 0.f);
    else if constexpr (MODE == 2) return v > 0.f ? v : 0.2f * v;
    else return v;
}

// ---------------------------------------------------------------------------
// Weight folds. ws layout (floats):
//   WA[128*64]@0  bA[64]@8192  cA[64]@8256  WB[64*16]@8320  bB[16]@9344
//   cB[16]@9360  T2[64*32]@9376  v1[128]@11424  v2[32]@11552  T1[128*128]@16384
// ---------------------------------------------------------------------------
__global__ __launch_bounds__(256) void fold1(
    const float* __restrict__ W1, const float* __restrict__ b1,
    const float* __restrict__ Wg1,
    const float* __restrict__ W2, const float* __restrict__ b2,
    const float* __restrict__ Wg2, float* __restrict__ ws) {
    float* T2 = ws + 9376;
    float* v1 = ws + 11424;
    float* v2 = ws + 11552;
    float* T1 = ws + 16384;
    const int tid = threadIdx.x, b = blockIdx.x;
    if (b < 16) {                       // T1 = W1 @ Wg1
        int i = b * 8 + (tid >> 5), j4 = (tid & 31) << 2;
        float4 acc = {0, 0, 0, 0};
        for (int k = 0; k < 128; ++k) {
            float a = W1[i * 128 + k];
            float4 g = *(const float4*)&Wg1[k * 128 + j4];
            acc.x += a * g.x; acc.y += a * g.y; acc.z += a * g.z; acc.w += a * g.w;
        }
        *(float4*)&T1[i * 128 + j4] = acc;
    } else if (b == 16) {
        if (tid < 128) {
            float s = 0;
            for (int k = 0; k < 128; ++k) s += b1[k] * Wg1[k * 128 + tid];
            v1[tid] = s;
        } else if (tid < 160) {
            int j = tid - 128;
            float s = 0;
            for (int k = 0; k < 32; ++k) s += b2[k] * Wg2[k * 32 + j];
            v2[j] = s;
        }
    } else {                            // T2 = W2 @ Wg2
        for (int o4 = tid; o4 < 64 * 8; o4 += 256) {
            int i = o4 >> 3, j4 = (o4 & 7) << 2;
            float4 acc = {0, 0, 0, 0};
            for (int k = 0; k < 32; ++k) {
                float a = W2[i * 32 + k];
                float4 g = *(const float4*)&Wg2[k * 32 + j4];
                acc.x += a * g.x; acc.y += a * g.y; acc.z += a * g.z; acc.w += a * g.w;
            }
            *(float4*)&T2[i * 32 + j4] = acc;
        }
    }
}

__global__ __launch_bounds__(256) void fold2(
    const float* __restrict__ Wm1, const float* __restrict__ bm1,
    const float* __restrict__ bg1,
    const float* __restrict__ W3, const float* __restrict__ b3,
    const float* __restrict__ bg2, float* __restrict__ ws) {
    float* WA = ws + 0;
    float* bA = ws + 8192;
    float* cA = ws + 8256;
    float* WB = ws + 8320;
    float* bB = ws + 9344;
    float* cB = ws + 9360;
    const float* T2 = ws + 9376;
    const float* v1 = ws + 11424;
    const float* v2 = ws + 11552;
    const float* T1 = ws + 16384;
    const int tid = threadIdx.x, b = blockIdx.x;
    if (b < 8) {                        // WA = T1 @ Wm1
        int i = b * 16 + (tid >> 4), j4 = (tid & 15) << 2;
        float4 acc = {0, 0, 0, 0};
        for (int k = 0; k < 128; ++k) {
            float a = T1[i * 128 + k];
            float4 g = *(const float4*)&Wm1[k * 64 + j4];
            acc.x += a * g.x; acc.y += a * g.y; acc.z += a * g.z; acc.w += a * g.w;
        }
        *(float4*)&WA[i * 64 + j4] = acc;
    } else if (b == 8) {
        if (tid < 64) {
            float s = 0, c = 0;
            for (int k = 0; k < 128; ++k) {
                s += v1[k] * Wm1[k * 64 + tid];
                c += bg1[k] * Wm1[k * 64 + tid];
            }
            bA[tid] = s; cA[tid] = c + bm1[tid];
        } else if (tid < 80) {
            int j = tid - 64;
            float s = 0, c = 0;
            for (int k = 0; k < 32; ++k) {
                s += v2[k] * W3[k * 16 + j];
                c += bg2[k] * W3[k * 16 + j];
            }
            bB[j] = s; cB[j] = c + b3[j];
        }
    } else {                            // WB = T2 @ W3
        int i = tid >> 2, j4 = (tid & 3) << 2;
        float4 acc = {0, 0, 0, 0};
        for (int k = 0; k < 32; ++k) {
            float a = T2[i * 32 + k];
            float4 g = *(const float4*)&W3[k * 16 + j4];
            acc.x += a * g.x; acc.y += a * g.y; acc.z += a * g.z; acc.w += a * g.w;
        }
        *(float4*)&WB[i * 16 + j4] = acc;
    }
}

// ---------------------------------------------------------------------------
// sA GEMM: St = bf16((x @ WA + bA)^T)
// ---------------------------------------------------------------------------
__global__ __launch_bounds__(256) void gemm_sA(
    const float* __restrict__ in, const float* __restrict__ W,
    const float* __restrict__ bias, u16* __restrict__ St) {
    constexpr int K = 128, M = 64, RB = 32;
    __shared__ float in_t[K][RB + 4];
    __shared__ float w_s[K * M];
    __shared__ float bias_s[M];
    const int tid = threadIdx.x;
    const int b0 = blockIdx.x * RB;
    for (int g = tid; g < RB * (K / 4); g += 256) {
        int r = g / (K / 4), c4 = g % (K / 4);
        float4 v = *(const float4*)&in[(size_t)(b0 + r) * K + c4 * 4];
        in_t[c4 * 4 + 0][r] = v.x;
        in_t[c4 * 4 + 1][r] = v.y;
        in_t[c4 * 4 + 2][r] = v.z;
        in_t[c4 * 4 + 3][r] = v.w;
    }
    for (int g = tid; g < K * M / 4; g += 256)
        ((float4*)w_s)[g] = ((const float4*)W)[g];
    if (tid < M) bias_s[tid] = bias[tid];
    __syncthreads();

    const int tx = tid & 15, ty = tid >> 4;
    const int c0 = tx * 4, r0 = ty * 2;
    float acc[2][4] = {};
    for (int k = 0; k < K; ++k) {
        float a0 = in_t[k][r0], a1 = in_t[k][r0 + 1];
        float4 wv = *(const float4*)&w_s[k * M + c0];
        acc[0][0] += a0 * wv.x; acc[0][1] += a0 * wv.y; acc[0][2] += a0 * wv.z; acc[0][3] += a0 * wv.w;
        acc[1][0] += a1 * wv.x; acc[1][1] += a1 * wv.y; acc[1][2] += a1 * wv.z; acc[1][3] += a1 * wv.w;
    }
#pragma unroll
    for (int m = 0; m < 2; ++m)
#pragma unroll
        for (int n = 0; n < 4; ++n)
            St[(size_t)(c0 + n) * NROWS + (b0 + r0 + m)] = f2b(acc[m][n] + bias_s[c0 + n]);
}

// ---------------------------------------------------------------------------
// Fused med chain + reduce1 (16 rows/block)
// ---------------------------------------------------------------------------
template<int K, int M, int AOUT, int OMODE>  // OMODE 0: panel; 1: panel+global; 2: St only
__device__ __forceinline__ void layer_step(
    const float (*pin)[17], const float* __restrict__ w,
    const float* __restrict__ bias,
    float (*pout)[17], float* __restrict__ gout, u16* __restrict__ stout,
    int b0, int tid) {
    constexpr int TXs = M / 4;
    constexpr int TYs = 256 / TXs;
    constexpr int TMs = 16 / TYs;
    static_assert(TMs >= 1, "cfg");
    const int tx = tid % TXs, ty = tid / TXs;
    const int c0 = tx * 4, r0 = ty * TMs;
    float acc[TMs][4] = {};
    for (int k = 0; k < K; ++k) {
        float4 wv = *(const float4*)&w[k * M + c0];
#pragma unroll
        for (int m = 0; m < TMs; ++m) {
            float a = pin[k][r0 + m];
            acc[m][0] += a * wv.x; acc[m][1] += a * wv.y;
            acc[m][2] += a * wv.z; acc[m][3] += a * wv.w;
        }
    }
#pragma unroll
    for (int m = 0; m < TMs; ++m) {
        float v[4];
#pragma unroll
        for (int n = 0; n < 4; ++n) {
            float bv = bias ? bias[c0 + n] : 0.f;
            v[n] = actf<AOUT>(acc[m][n] + bv);
        }
        if constexpr (OMODE != 2) {
#pragma unroll
            for (int n = 0; n < 4; ++n) pout[c0 + n][r0 + m] = v[n];
        }
        if constexpr (OMODE == 1) {
            float4 o = {v[0], v[1], v[2], v[3]};
            *(float4*)&gout[(size_t)(b0 + r0 + m) * M + c0] = o;
        }
        if constexpr (OMODE == 2) {
#pragma unroll
            for (int n = 0; n < 4; ++n)
                stout[(size_t)(c0 + n) * NROWS + (b0 + r0 + m)] = f2b(v[n]);
        }
    }
}

template<int KS>
__global__ __launch_bounds__(256) void med_chain(
    const u16* __restrict__ P, const float* __restrict__ cA,
    const float* __restrict__ Wm2, const float* __restrict__ bm2,
    const float* __restrict__ Wm3, const float* __restrict__ bm3,
    const float* __restrict__ Wm4, const float* __restrict__ bm4,
    const float* __restrict__ Wgh,
    float* __restrict__ h4, u16* __restrict__ St) {
    __shared__ __align__(16) float P0[64][17];
    __shared__ __align__(16) float P1[128][17];
    __shared__ __align__(16) float P2[64][17];
    const int tid = threadIdx.x;
    const int b0 = blockIdx.x * 16;
    constexpr size_t STR = (size_t)NROWS * 64;

    {
        int r = tid >> 4, c4 = (tid & 15) * 4;
        float s[4];
        float4 cv = *(const float4*)&cA[c4];
        s[0] = cv.x; s[1] = cv.y; s[2] = cv.z; s[3] = cv.w;
#pragma unroll
        for (int k = 0; k < KS; ++k) {
            bf16x4 v = *(const bf16x4*)(P + (size_t)k * STR + (size_t)(b0 + r) * 64 + c4);
#pragma unroll
            for (int j = 0; j < 4; ++j) s[j] += b2f((u16)v[j]);
        }
#pragma unroll
        for (int j = 0; j < 4; ++j) P0[c4 + j][r] = actf<2>(s[j]);
    }
    __syncthreads();
    layer_step<64, 128, 2, 0>(P0, Wm2, bm2, P1, nullptr, nullptr, b0, tid);
    __syncthreads();
    layer_step<128, 64, 2, 0>(P1, Wm3, bm3, P2, nullptr, nullptr, b0, tid);
    __syncthreads();
    layer_step<64, 64, 1, 1>(P2, Wm4, bm4, P0, h4, nullptr, b0, tid);
    __syncthreads();
    layer_step<64, 64, 0, 2>(P0, Wgh, nullptr, nullptr, nullptr, St, b0, tid);
}

// ---------------------------------------------------------------------------
// Fused reduce2 + sB GEMM
// ---------------------------------------------------------------------------
template<int KS>
__global__ __launch_bounds__(256) void gemm_sB(
    const u16* __restrict__ P, const float* __restrict__ bgh,
    const float* __restrict__ h4,
    const float* __restrict__ WB, const float* __restrict__ bB,
    u16* __restrict__ St) {
    constexpr int K = 64, M = 16, RB = 32;
    __shared__ float in_t[K][RB + 4];
    __shared__ float w_s[K * M];
    const int tid = threadIdx.x;
    const int b0 = blockIdx.x * RB;
    constexpr size_t STR = (size_t)NROWS * 64;

    for (int g = tid; g < RB * 16; g += 256) {
        int r = g >> 4, c4 = (g & 15) * 4;
        float s[4];
        float4 bv = *(const float4*)&bgh[c4];
        s[0] = bv.x; s[1] = bv.y; s[2] = bv.z; s[3] = bv.w;
#pragma unroll
        for (int k = 0; k < KS; ++k) {
            bf16x4 v = *(const bf16x4*)(P + (size_t)k * STR + (size_t)(b0 + r) * 64 + c4);
#pragma unroll
            for (int j = 0; j < 4; ++j) s[j] += b2f((u16)v[j]);
        }
        float4 hv = *(const float4*)&h4[(size_t)(b0 + r) * 64 + c4];
        in_t[c4 + 0][r] = fmaxf(s[0] + hv.x, 0.f);
        in_t[c4 + 1][r] = fmaxf(s[1] + hv.y, 0.f);
        in_t[c4 + 2][r] = fmaxf(s[2] + hv.z, 0.f);
        in_t[c4 + 3][r] = fmaxf(s[3] + hv.w, 0.f);
    }
    for (int g = tid; g < K * M / 4; g += 256)
        ((float4*)w_s)[g] = ((const float4*)WB)[g];
    __syncthreads();

    const int tx = tid & 7, ty = tid >> 3;
    const int c0 = tx * 2, r0 = ty;
    float a0 = 0, a1 = 0;
    for (int k = 0; k < K; ++k) {
        float a = in_t[k][r0];
        a0 += a * w_s[k * M + c0];
        a1 += a * w_s[k * M + c0 + 1];
    }
    St[(size_t)(c0 + 0) * NROWS + (b0 + r0)] = f2b(a0 + bB[c0]);
    St[(size_t)(c0 + 1) * NROWS + (b0 + r0)] = f2b(a1 + bB[c0 + 1]);
}

// ---------------------------------------------------------------------------
// Pass-1 aggregation: BK=256 (1KB per-row DRAM extents — granularity probe),
// reg-staged, 1-deep prefetch.  MODE 1: A = bf16(adj*dis) on the fly (NT
// reads) + write Abf.  MODE 2: on the fly, no write (fallback).
// LDS 64KB total -> 2 blocks/CU; in-flight bytes/CU ~4MB >> latency-BW need.
// ---------------------------------------------------------------------------
#define LOADA_F(KC) \
    _Pragma("unroll") for (int r = 0; r < AR4; ++r) { \
        int e4 = r * 256 + tid; \
        size_t g = (size_t)(i0 + (e4 >> ASH)) * NROWS + (KC) + (e4 & (AGR - 1)) * 4; \
        rAa[r] = __builtin_nontemporal_load((const f32x4*)(adj + g)); \
        rAd[r] = __builtin_nontemporal_load((const f32x4*)(dis + g)); \
    }

#define STOREA_F(KC) \
    _Pragma("unroll") for (int r = 0; r < AR4; ++r) { \
        int e4 = r * 256 + tid; int row = e4 >> ASH; int col = (e4 & (AGR - 1)) * 4; \
        bf16x4 v; \
        _Pragma("unroll") for (int j = 0; j < 4; ++j) v[j] = (short)f2b(rAa[r][j] * rAd[r][j]); \
        if constexpr (MODE == 1) \
            *(bf16x4*)(Abf + (size_t)(i0 + row) * NROWS + (KC) + col) = v; \
        int bo = ((row * BK + col) * 2) ^ ((row & 7) << 4); \
        *(bf16x4*)((char*)As + bo) = v; \
    }

#define LOADB_C(KC) \
    _Pragma("unroll") for (int r = 0; r < BR8; ++r) { \
        int e8 = r * 256 + tid; \
        rB[r] = *(const bf16x8*)(St + (size_t)(e8 >> BSH) * NROWS + (KC) + (e8 & (BGR - 1)) * 8); \
    }

#define STOREB_C() \
    _Pragma("unroll") for (int r = 0; r < BR8; ++r) { \
        int e8 = r * 256 + tid; int c = e8 >> BSH; int col = (e8 & (BGR - 1)) * 8; \
        int bo = ((c * BK + col) * 2) ^ ((c & 7) << 4); \
        *(bf16x8*)((char*)Bs + bo) = rB[r]; \
    }

#define MFMA_C() \
    _Pragma("unroll") \
    for (int ks = 0; ks < BK; ks += 32) { \
        int ao = ((arow * BK + ks + kb) * 2) ^ ((arow & 7) << 4); \
        bf16x8 af = *(const bf16x8*)((const char*)As + ao); \
        _Pragma("unroll") \
        for (int ct = 0; ct < CT; ++ct) { \
            int bcol = ct * 16 + l15; \
            int bo = ((bcol * BK + ks + kb) * 2) ^ ((bcol & 7) << 4); \
            bf16x8 bf = *(const bf16x8*)((const char*)Bs + bo); \
            acc[ct] = __builtin_amdgcn_mfma_f32_16x16x32_bf16(af, bf, acc[ct], 0, 0, 0); \
        } \
    }

template<int F, int MODE, int KS>
__global__ __launch_bounds__(256) void agg_cold(
    u16* __restrict__ Abf, const float* __restrict__ adj,
    const float* __restrict__ dis, const u16* __restrict__ St,
    u16* __restrict__ Pout) {
    constexpr int CT = F / 16;
    constexpr int BK = 256;
    constexpr int KCH = NROWS / KS;
    constexpr int NCH = KCH / BK;                // 4
    constexpr int AGR = BK / 4;                  // 4-float groups per row
    constexpr int ASH = (AGR == 64) ? 6 : 5;
    constexpr int BGR = BK / 8;                  // 8-elem groups per row
    constexpr int BSH = (BGR == 32) ? 5 : 4;
    constexpr int AR4 = (64 * BK) / (256 * 4);   // 16
    constexpr int BR8 = (F * BK) / (256 * 8);    // 8 (F=64) / 2 (F=16)
    __shared__ __align__(16) u16 As[64 * BK];    // 32KB
    __shared__ __align__(16) u16 Bs[F * BK];     // 32KB / 8KB
    const int tid  = threadIdx.x;
    const int lane = tid & 63;
    const int wid  = tid >> 6;
    const int i0   = blockIdx.x * 64;
    const int ky   = blockIdx.y;
    const int l15  = lane & 15;
    const int kb   = (lane >> 4) * 8;
    const int k0   = ky * KCH;
    const int arow = wid * 16 + l15;
    f32x4 acc[CT] = {};
    f32x4 rAa[AR4], rAd[AR4];
    bf16x8 rB[BR8];

    LOADA_F(k0)
    LOADB_C(k0)
    for (int ch = 0; ch < NCH; ++ch) {
        const int kc = k0 + ch * BK;
        __syncthreads();
        STOREA_F(kc)
        STOREB_C()
        __syncthreads();
        if (ch + 1 < NCH) { LOADA_F(kc + BK) LOADB_C(kc + BK) }
        MFMA_C()
    }
    u16* P = Pout + (size_t)ky * ((size_t)NROWS * F);
    const int rb = i0 + wid * 16 + (lane >> 4) * 4;
#pragma unroll
    for (int ct = 0; ct < CT; ++ct)
#pragma unroll
        for (int i = 0; i < 4; ++i)
            P[(size_t)(rb + i) * F + ct * 16 + l15] = f2b(acc[ct][i]);
}
#undef LOADA_F
#undef STOREA_F
#undef LOADB_C
#undef STOREB_C
#undef MFMA_C

// ---------------------------------------------------------------------------
// Warm-pass aggregation (unchanged from R12): A from Abf (L3-resident) via
// global_load_lds width=16, double-buffered, pre-swizzled global source.
// ---------------------------------------------------------------------------
template<int F>
__global__ __launch_bounds__(256) void agg_warm(
    const u16* __restrict__ Abf, const u16* __restrict__ St,
    u16* __restrict__ Pout) {
    constexpr int CT = F / 16;
    constexpr int BK = 64;
    constexpr int KS = 8;
    constexpr int KCH = NROWS / KS;
    constexpr int NCH = KCH / BK;        // 16
    constexpr int BSLOT = F * BK / 8;
    __shared__ __align__(16) u16 As[2][64 * BK];
    __shared__ __align__(16) u16 Bs[F * BK];
    const int tid  = threadIdx.x;
    const int lane = tid & 63;
    const int wid  = tid >> 6;
    const int i0   = blockIdx.x * 64;
    const int ky   = blockIdx.y;
    const int l15  = lane & 15;
    const int kb   = (lane >> 4) * 8;
    const int k0   = ky * KCH;
    const int arow = wid * 16 + l15;
    f32x4 acc[CT] = {};

    const int arl  = lane >> 3;
    const int agrp = (lane & 7) ^ arl;

#if HAS_GLL
#define ISSUE_A(BUF, KC) \
    _Pragma("unroll") for (int i = 0; i < 2; ++i) { \
        int r0_ = wid * 16 + i * 8; \
        const u16* gp_ = Abf + (size_t)(i0 + r0_ + arl) * NROWS + (KC) + agrp * 8; \
        u16* lp_ = &As[BUF][r0_ * BK]; \
        __builtin_amdgcn_global_load_lds((glb_cvoid*)gp_, (lds_void*)lp_, 16, 0, 0); \
    }
#define STOREA_FB(BUF)
#else
    bf16x8 rA0, rA1;
#define ISSUE_A(BUF, KC) { \
        int e0 = tid, e1 = tid + 256; \
        rA0 = *(const bf16x8*)(Abf + (size_t)(i0 + (e0 >> 3)) * NROWS + (KC) + (((e0 & 7) ^ ((e0 >> 3) & 7)) * 8)); \
        rA1 = *(const bf16x8*)(Abf + (size_t)(i0 + (e1 >> 3)) * NROWS + (KC) + (((e1 & 7) ^ ((e1 >> 3) & 7)) * 8)); \
    }
#define STOREA_FB(BUF) { \
        *(bf16x8*)(&As[BUF][(size_t)tid * 8]) = rA0; \
        *(bf16x8*)(&As[BUF][(size_t)(tid + 256) * 8]) = rA1; \
    }
#endif

    bf16x8 rB0, rB1;
#define LOADB_W(KC) { \
        if constexpr (F == 64) { \
            int c0_ = tid >> 3, g0_ = tid & 7; \
            int c1_ = (tid + 256) >> 3, g1_ = (tid + 256) & 7; \
            rB0 = *(const bf16x8*)(St + (size_t)c0_ * NROWS + (KC) + ((g0_ ^ (c0_ & 7)) * 8)); \
            rB1 = *(const bf16x8*)(St + (size_t)c1_ * NROWS + (KC) + ((g1_ ^ (c1_ & 7)) * 8)); \
        } else { \
            if (tid < BSLOT) { \
                int c0_ = tid >> 3, g0_ = tid & 7; \
                rB0 = *(const bf16x8*)(St + (size_t)c0_ * NROWS + (KC) + ((g0_ ^ (c0_ & 7)) * 8)); \
            } \
        } \
    }
#define STOREB_W() { \
        if constexpr (F == 64) { \
            *(bf16x8*)(&Bs[(size_t)tid * 8]) = rB0; \
            *(bf16x8*)(&Bs[(size_t)(tid + 256) * 8]) = rB1; \
        } else { \
            if (tid < BSLOT) *(bf16x8*)(&Bs[(size_t)tid * 8]) = rB0; \
        } \
    }

    ISSUE_A(0, k0)
    LOADB_W(k0)
    int cur = 0;
    for (int ch = 0; ch < NCH; ++ch) {
        const int kc = k0 + ch * BK;
        __syncthreads();
        STOREB_W()
        STOREA_FB(cur)
        __syncthreads();
        if (ch + 1 < NCH) {
            ISSUE_A(cur ^ 1, kc + BK)
            LOADB_W(kc + BK)
        }
#pragma unroll
        for (int ks = 0; ks < BK; ks += 32) {
            int ao = ((arow * BK + ks + kb) * 2) ^ ((arow & 7) << 4);
            bf16x8 af = *(const bf16x8*)((const char*)As[cur] + ao);
#pragma unroll
            for (int ct = 0; ct < CT; ++ct) {
                int bcol = ct * 16 + l15;
                int bo = ((bcol * BK + ks + kb) * 2) ^ ((bcol & 7) << 4);
                bf16x8 bf = *(const bf16x8*)((const char*)Bs + bo);
                acc[ct] = __builtin_amdgcn_mfma_f32_16x16x32_bf16(af, bf, acc[ct], 0, 0, 0);
            }
        }
        cur ^= 1;
    }
#undef ISSUE_A
#undef STOREA_FB
#undef LOADB_W
#undef STOREB_W
    u16* P = Pout + (size_t)ky * ((size_t)NROWS * F);
    const int rb = i0 + wid * 16 + (lane >> 4) * 4;
#pragma unroll
    for (int ct = 0; ct < CT; ++ct)
#pragma unroll
        for (int i = 0; i < 4; ++i)
            P[(size_t)(rb + i) * F + ct * 16 + l15] = f2b(acc[ct][i]);
}

// ---------------------------------------------------------------------------
// out = sum_{ky} b2f(P[ky]) + bias[col]   (final pass-3 reduce, F=16)
// ---------------------------------------------------------------------------
template<int F, int KS>
__global__ __launch_bounds__(256) void reduce_add(
    const u16* __restrict__ P, const float* __restrict__ bias,
    float* __restrict__ out) {
    constexpr int TOT8 = NROWS * F / 8;
    int i8 = blockIdx.x * 256 + threadIdx.x;
    if (i8 >= TOT8) return;
    constexpr size_t STR = (size_t)NROWS * F;
    float s[8] = {};
#pragma unroll
    for (int k = 0; k < KS; ++k) {
        bf16x8 v = *(const bf16x8*)(P + (size_t)k * STR + (size_t)i8 * 8);
#pragma unroll
        for (int j = 0; j < 8; ++j) s[j] += b2f((u16)v[j]);
    }
    const int c0 = (i8 * 8) % F;
#pragma unroll
    for (int j = 0; j < 8; ++j) s[j] += bias[c0 + j];
    float4* o4 = (float4*)(out + (size_t)i8 * 8);
    float4 oa = {s[0], s[1], s[2], s[3]}, ob = {s[4], s[5], s[6], s[7]};
    o4[0] = oa; o4[1] = ob;
}

extern "C" void kernel_launch(void* const* d_in, const int* in_sizes, int n_in,
                              void* d_out, int out_size, void* d_ws, size_t ws_size,
                              hipStream_t stream) {
    const float* x   = (const float*)d_in[0];
    const float* adj = (const float*)d_in[1];
    const float* dis = (const float*)d_in[2];
    const float* W1  = (const float*)d_in[3];
    const float* b1  = (const float*)d_in[4];
    const float* Wg1 = (const float*)d_in[5];
    const float* bg1 = (const float*)d_in[6];
    const float* Wm1 = (const float*)d_in[7];
    const float* bm1 = (const float*)d_in[8];
    const float* Wm2 = (const float*)d_in[9];
    const float* bm2 = (const float*)d_in[10];
    const float* Wm3 = (const float*)d_in[11];
    const float* bm3 = (const float*)d_in[12];
    const float* Wm4 = (const float*)d_in[13];
    const float* bm4 = (const float*)d_in[14];
    const float* Wgh = (const float*)d_in[15];
    const float* bgh = (const float*)d_in[16];
    const float* W2  = (const float*)d_in[17];
    const float* b2  = (const float*)d_in[18];
    const float* Wg2 = (const float*)d_in[19];
    const float* bg2 = (const float*)d_in[20];
    const float* W3  = (const float*)d_in[21];
    const float* b3  = (const float*)d_in[22];
    float* ws  = (float*)d_ws;
    float* out = (float*)d_out;

    constexpr int KS = 8;
    const size_t ABF_FLOATS = (size_t)NROWS * NROWS / 2;    // bf16 Abf: 128MB
    const size_t P_FLOATS = (size_t)KS * NROWS * 64 / 2;    // bf16 partials (8MB)
    const size_t BASE_FLOATS = 40960 + 262144 + P_FLOATS + 524288;
    const size_t NEED_PRE_BYTES = (ABF_FLOATS + BASE_FLOATS) * 4ULL;  // ~140MB
    const bool pre = ws_size >= NEED_PRE_BYTES;

    float* base = ws + (pre ? ABF_FLOATS : 0);
    float* wsW  = base;                       // fold area: 40960 floats
    float* St_f = wsW + 40960;                // S^T bf16 [64][8192]
    float* P_f  = St_f + 262144;              // partials bf16: KS*8192*64
    float* h4   = P_f + P_FLOATS;             // [8192,64] fp32

    u16* Abf = (u16*)ws;
    u16* St  = (u16*)St_f;
    u16* P   = (u16*)P_f;
    const float* WA = wsW + 0;
    const float* bA = wsW + 8192;
    const float* cA = wsW + 8256;
    const float* WB = wsW + 8320;
    const float* bB = wsW + 9344;
    const float* cB = wsW + 9360;

    fold1<<<18, 256, 0, stream>>>(W1, b1, Wg1, W2, b2, Wg2, wsW);
    fold2<<<10, 256, 0, stream>>>(Wm1, bm1, bg1, W3, b3, bg2, wsW);

    // pass 1 (fused converter): sA^T bf16 ; P = split-K(A @ sA)
    gemm_sA<<<256, 256, 0, stream>>>(x, WA, bA, St);
    if (pre) agg_cold<64, 1, KS><<<dim3(128, KS), 256, 0, stream>>>(Abf, adj, dis, St, P);
    else     agg_cold<64, 2, KS><<<dim3(128, KS), 256, 0, stream>>>(nullptr, adj, dis, St, P);

    // fused reduce1 + med chain: P,cA -> h4 (global) + s2^T (St, bf16)
    med_chain<KS><<<512, 256, 0, stream>>>(P, cA, Wm2, bm2, Wm3, bm3, Wm4, bm4, Wgh, h4, St);

    // pass 2: P = split-K(A @ s2)   (A from L3-warm Abf via global_load_lds)
    if (pre) agg_warm<64><<<dim3(128, KS), 256, 0, stream>>>(Abf, St, P);
    else     agg_cold<64, 2, KS><<<dim3(128, KS), 256, 0, stream>>>(nullptr, adj, dis, St, P);

    // fused reduce2 + sB GEMM
    gemm_sB<KS><<<256, 256, 0, stream>>>(P, bgh, h4, WB, bB, St);

    // pass 3: P = split-K(A @ sB) ; out = sumP + cB
    if (pre) agg_warm<16><<<dim3(128, KS), 256, 0, stream>>>(Abf, St, P);
    else     agg_cold<16, 2, KS><<<dim3(128, KS), 256, 0, stream>>>(nullptr, adj, dis, St, P);
    reduce_add<16, KS><<<64, 256, 0, stream>>>(P, cB, out);
}

// Round 14
// 309.895 us; speedup vs baseline: 1.0364x; 1.0364x over previous
//
#include <hip/hip_runtime.h>
#include <hip/hip_bf16.h>

#define NROWS 8192
typedef unsigned short u16;
typedef short bf16x8 __attribute__((ext_vector_type(8)));
typedef short bf16x4 __attribute__((ext_vector_type(4)));
typedef float f32x4 __attribute__((ext_vector_type(4)));

#if __has_builtin(__builtin_amdgcn_global_load_lds)
#define HAS_GLL 1
typedef __attribute__((address_space(3))) void lds_void;
typedef __attribute__((address_space(1))) const void glb_cvoid;
#else
#define HAS_GLL 0
#endif

__device__ __forceinline__ u16 f2b(float f) {   // fp32 -> bf16 RNE
    unsigned u = __float_as_uint(f);
    unsigned r = (u + 0x7fffu + ((u >> 16) & 1u)) >> 16;
    return (u16)r;
}
__device__ __forceinline__ float b2f(u16 v) {
    return __uint_as_float(((unsigned)v) << 16);
}

template<int MODE> __device__ __forceinline__ float actf(float v) {
    if constexpr (MODE == 1) return fmaxf(v, 0.f);
    else if constexpr (MODE == 2) return v > 0.f ? v : 0.2f * v;
    else return v;
}

// ---------------------------------------------------------------------------
// Weight folds. ws layout (floats):
//   WA[128*64]@0  bA[64]@8192  cA[64]@8256  WB[64*16]@8320  bB[16]@9344
//   cB[16]@9360  T2[64*32]@9376  v1[128]@11424  v2[32]@11552  T1[128*128]@16384
// ---------------------------------------------------------------------------
__global__ __launch_bounds__(256) void fold1(
    const float* __restrict__ W1, const float* __restrict__ b1,
    const float* __restrict__ Wg1,
    const float* __restrict__ W2, const float* __restrict__ b2,
    const float* __restrict__ Wg2, float* __restrict__ ws) {
    float* T2 = ws + 9376;
    float* v1 = ws + 11424;
    float* v2 = ws + 11552;
    float* T1 = ws + 16384;
    const int tid = threadIdx.x, b = blockIdx.x;
    if (b < 16) {                       // T1 = W1 @ Wg1
        int i = b * 8 + (tid >> 5), j4 = (tid & 31) << 2;
        float4 acc = {0, 0, 0, 0};
        for (int k = 0; k < 128; ++k) {
            float a = W1[i * 128 + k];
            float4 g = *(const float4*)&Wg1[k * 128 + j4];
            acc.x += a * g.x; acc.y += a * g.y; acc.z += a * g.z; acc.w += a * g.w;
        }
        *(float4*)&T1[i * 128 + j4] = acc;
    } else if (b == 16) {
        if (tid < 128) {
            float s = 0;
            for (int k = 0; k < 128; ++k) s += b1[k] * Wg1[k * 128 + tid];
            v1[tid] = s;
        } else if (tid < 160) {
            int j = tid - 128;
            float s = 0;
            for (int k = 0; k < 32; ++k) s += b2[k] * Wg2[k * 32 + j];
            v2[j] = s;
        }
    } else {                            // T2 = W2 @ Wg2
        for (int o4 = tid; o4 < 64 * 8; o4 += 256) {
            int i = o4 >> 3, j4 = (o4 & 7) << 2;
            float4 acc = {0, 0, 0, 0};
            for (int k = 0; k < 32; ++k) {
                float a = W2[i * 32 + k];
                float4 g = *(const float4*)&Wg2[k * 32 + j4];
                acc.x += a * g.x; acc.y += a * g.y; acc.z += a * g.z; acc.w += a * g.w;
            }
            *(float4*)&T2[i * 32 + j4] = acc;
        }
    }
}

__global__ __launch_bounds__(256) void fold2(
    const float* __restrict__ Wm1, const float* __restrict__ bm1,
    const float* __restrict__ bg1,
    const float* __restrict__ W3, const float* __restrict__ b3,
    const float* __restrict__ bg2, float* __restrict__ ws) {
    float* WA = ws + 0;
    float* bA = ws + 8192;
    float* cA = ws + 8256;
    float* WB = ws + 8320;
    float* bB = ws + 9344;
    float* cB = ws + 9360;
    const float* T2 = ws + 9376;
    const float* v1 = ws + 11424;
    const float* v2 = ws + 11552;
    const float* T1 = ws + 16384;
    const int tid = threadIdx.x, b = blockIdx.x;
    if (b < 8) {                        // WA = T1 @ Wm1
        int i = b * 16 + (tid >> 4), j4 = (tid & 15) << 2;
        float4 acc = {0, 0, 0, 0};
        for (int k = 0; k < 128; ++k) {
            float a = T1[i * 128 + k];
            float4 g = *(const float4*)&Wm1[k * 64 + j4];
            acc.x += a * g.x; acc.y += a * g.y; acc.z += a * g.z; acc.w += a * g.w;
        }
        *(float4*)&WA[i * 64 + j4] = acc;
    } else if (b == 8) {
        if (tid < 64) {
            float s = 0, c = 0;
            for (int k = 0; k < 128; ++k) {
                s += v1[k] * Wm1[k * 64 + tid];
                c += bg1[k] * Wm1[k * 64 + tid];
            }
            bA[tid] = s; cA[tid] = c + bm1[tid];
        } else if (tid < 80) {
            int j = tid - 64;
            float s = 0, c = 0;
            for (int k = 0; k < 32; ++k) {
                s += v2[k] * W3[k * 16 + j];
                c += bg2[k] * W3[k * 16 + j];
            }
            bB[j] = s; cB[j] = c + b3[j];
        }
    } else {                            // WB = T2 @ W3
        int i = tid >> 2, j4 = (tid & 3) << 2;
        float4 acc = {0, 0, 0, 0};
        for (int k = 0; k < 32; ++k) {
            float a = T2[i * 32 + k];
            float4 g = *(const float4*)&W3[k * 16 + j4];
            acc.x += a * g.x; acc.y += a * g.y; acc.z += a * g.z; acc.w += a * g.w;
        }
        *(float4*)&WB[i * 16 + j4] = acc;
    }
}

// ---------------------------------------------------------------------------
// sA GEMM: St = bf16((x @ WA + bA)^T)
// ---------------------------------------------------------------------------
__global__ __launch_bounds__(256) void gemm_sA(
    const float* __restrict__ in, const float* __restrict__ W,
    const float* __restrict__ bias, u16* __restrict__ St) {
    constexpr int K = 128, M = 64, RB = 32;
    __shared__ float in_t[K][RB + 4];
    __shared__ float w_s[K * M];
    __shared__ float bias_s[M];
    const int tid = threadIdx.x;
    const int b0 = blockIdx.x * RB;
    for (int g = tid; g < RB * (K / 4); g += 256) {
        int r = g / (K / 4), c4 = g % (K / 4);
        float4 v = *(const float4*)&in[(size_t)(b0 + r) * K + c4 * 4];
        in_t[c4 * 4 + 0][r] = v.x;
        in_t[c4 * 4 + 1][r] = v.y;
        in_t[c4 * 4 + 2][r] = v.z;
        in_t[c4 * 4 + 3][r] = v.w;
    }
    for (int g = tid; g < K * M / 4; g += 256)
        ((float4*)w_s)[g] = ((const float4*)W)[g];
    if (tid < M) bias_s[tid] = bias[tid];
    __syncthreads();

    const int tx = tid & 15, ty = tid >> 4;
    const int c0 = tx * 4, r0 = ty * 2;
    float acc[2][4] = {};
    for (int k = 0; k < K; ++k) {
        float a0 = in_t[k][r0], a1 = in_t[k][r0 + 1];
        float4 wv = *(const float4*)&w_s[k * M + c0];
        acc[0][0] += a0 * wv.x; acc[0][1] += a0 * wv.y; acc[0][2] += a0 * wv.z; acc[0][3] += a0 * wv.w;
        acc[1][0] += a1 * wv.x; acc[1][1] += a1 * wv.y; acc[1][2] += a1 * wv.z; acc[1][3] += a1 * wv.w;
    }
#pragma unroll
    for (int m = 0; m < 2; ++m)
#pragma unroll
        for (int n = 0; n < 4; ++n)
            St[(size_t)(c0 + n) * NROWS + (b0 + r0 + m)] = f2b(acc[m][n] + bias_s[c0 + n]);
}

// ---------------------------------------------------------------------------
// Fused med chain + reduce1 (16 rows/block)
// ---------------------------------------------------------------------------
template<int K, int M, int AOUT, int OMODE>  // OMODE 0: panel; 1: panel+global; 2: St only
__device__ __forceinline__ void layer_step(
    const float (*pin)[17], const float* __restrict__ w,
    const float* __restrict__ bias,
    float (*pout)[17], float* __restrict__ gout, u16* __restrict__ stout,
    int b0, int tid) {
    constexpr int TXs = M / 4;
    constexpr int TYs = 256 / TXs;
    constexpr int TMs = 16 / TYs;
    static_assert(TMs >= 1, "cfg");
    const int tx = tid % TXs, ty = tid / TXs;
    const int c0 = tx * 4, r0 = ty * TMs;
    float acc[TMs][4] = {};
    for (int k = 0; k < K; ++k) {
        float4 wv = *(const float4*)&w[k * M + c0];
#pragma unroll
        for (int m = 0; m < TMs; ++m) {
            float a = pin[k][r0 + m];
            acc[m][0] += a * wv.x; acc[m][1] += a * wv.y;
            acc[m][2] += a * wv.z; acc[m][3] += a * wv.w;
        }
    }
#pragma unroll
    for (int m = 0; m < TMs; ++m) {
        float v[4];
#pragma unroll
        for (int n = 0; n < 4; ++n) {
            float bv = bias ? bias[c0 + n] : 0.f;
            v[n] = actf<AOUT>(acc[m][n] + bv);
        }
        if constexpr (OMODE != 2) {
#pragma unroll
            for (int n = 0; n < 4; ++n) pout[c0 + n][r0 + m] = v[n];
        }
        if constexpr (OMODE == 1) {
            float4 o = {v[0], v[1], v[2], v[3]};
            *(float4*)&gout[(size_t)(b0 + r0 + m) * M + c0] = o;
        }
        if constexpr (OMODE == 2) {
#pragma unroll
            for (int n = 0; n < 4; ++n)
                stout[(size_t)(c0 + n) * NROWS + (b0 + r0 + m)] = f2b(v[n]);
        }
    }
}

template<int KS>
__global__ __launch_bounds__(256) void med_chain(
    const u16* __restrict__ P, const float* __restrict__ cA,
    const float* __restrict__ Wm2, const float* __restrict__ bm2,
    const float* __restrict__ Wm3, const float* __restrict__ bm3,
    const float* __restrict__ Wm4, const float* __restrict__ bm4,
    const float* __restrict__ Wgh,
    float* __restrict__ h4, u16* __restrict__ St) {
    __shared__ __align__(16) float P0[64][17];
    __shared__ __align__(16) float P1[128][17];
    __shared__ __align__(16) float P2[64][17];
    const int tid = threadIdx.x;
    const int b0 = blockIdx.x * 16;
    constexpr size_t STR = (size_t)NROWS * 64;

    {
        int r = tid >> 4, c4 = (tid & 15) * 4;
        float s[4];
        float4 cv = *(const float4*)&cA[c4];
        s[0] = cv.x; s[1] = cv.y; s[2] = cv.z; s[3] = cv.w;
#pragma unroll
        for (int k = 0; k < KS; ++k) {
            bf16x4 v = *(const bf16x4*)(P + (size_t)k * STR + (size_t)(b0 + r) * 64 + c4);
#pragma unroll
            for (int j = 0; j < 4; ++j) s[j] += b2f((u16)v[j]);
        }
#pragma unroll
        for (int j = 0; j < 4; ++j) P0[c4 + j][r] = actf<2>(s[j]);
    }
    __syncthreads();
    layer_step<64, 128, 2, 0>(P0, Wm2, bm2, P1, nullptr, nullptr, b0, tid);
    __syncthreads();
    layer_step<128, 64, 2, 0>(P1, Wm3, bm3, P2, nullptr, nullptr, b0, tid);
    __syncthreads();
    layer_step<64, 64, 1, 1>(P2, Wm4, bm4, P0, h4, nullptr, b0, tid);
    __syncthreads();
    layer_step<64, 64, 0, 2>(P0, Wgh, nullptr, nullptr, nullptr, St, b0, tid);
}

// ---------------------------------------------------------------------------
// Fused reduce2 + sB GEMM
// ---------------------------------------------------------------------------
template<int KS>
__global__ __launch_bounds__(256) void gemm_sB(
    const u16* __restrict__ P, const float* __restrict__ bgh,
    const float* __restrict__ h4,
    const float* __restrict__ WB, const float* __restrict__ bB,
    u16* __restrict__ St) {
    constexpr int K = 64, M = 16, RB = 32;
    __shared__ float in_t[K][RB + 4];
    __shared__ float w_s[K * M];
    const int tid = threadIdx.x;
    const int b0 = blockIdx.x * RB;
    constexpr size_t STR = (size_t)NROWS * 64;

    for (int g = tid; g < RB * 16; g += 256) {
        int r = g >> 4, c4 = (g & 15) * 4;
        float s[4];
        float4 bv = *(const float4*)&bgh[c4];
        s[0] = bv.x; s[1] = bv.y; s[2] = bv.z; s[3] = bv.w;
#pragma unroll
        for (int k = 0; k < KS; ++k) {
            bf16x4 v = *(const bf16x4*)(P + (size_t)k * STR + (size_t)(b0 + r) * 64 + c4);
#pragma unroll
            for (int j = 0; j < 4; ++j) s[j] += b2f((u16)v[j]);
        }
        float4 hv = *(const float4*)&h4[(size_t)(b0 + r) * 64 + c4];
        in_t[c4 + 0][r] = fmaxf(s[0] + hv.x, 0.f);
        in_t[c4 + 1][r] = fmaxf(s[1] + hv.y, 0.f);
        in_t[c4 + 2][r] = fmaxf(s[2] + hv.z, 0.f);
        in_t[c4 + 3][r] = fmaxf(s[3] + hv.w, 0.f);
    }
    for (int g = tid; g < K * M / 4; g += 256)
        ((float4*)w_s)[g] = ((const float4*)WB)[g];
    __syncthreads();

    const int tx = tid & 7, ty = tid >> 3;
    const int c0 = tx * 2, r0 = ty;
    float a0 = 0, a1 = 0;
    for (int k = 0; k < K; ++k) {
        float a = in_t[k][r0];
        a0 += a * w_s[k * M + c0];
        a1 += a * w_s[k * M + c0 + 1];
    }
    St[(size_t)(c0 + 0) * NROWS + (b0 + r0)] = f2b(a0 + bB[c0]);
    St[(size_t)(c0 + 1) * NROWS + (b0 + r0)] = f2b(a1 + bB[c0 + 1]);
}

// ---------------------------------------------------------------------------
// Pass-1 aggregation (best measured: R9/R12): BK=128, reg-staged, 1-deep
// prefetch.  MODE 1: A = bf16(adj*dis) on the fly (NT reads) + write Abf.
// MODE 2: on the fly, no write (fallback).
// ---------------------------------------------------------------------------
#define LOADA_F(KC) \
    _Pragma("unroll") for (int r = 0; r < AR4; ++r) { \
        int e4 = r * 256 + tid; \
        size_t g = (size_t)(i0 + (e4 >> 5)) * NROWS + (KC) + (e4 & 31) * 4; \
        rAa[r] = __builtin_nontemporal_load((const f32x4*)(adj + g)); \
        rAd[r] = __builtin_nontemporal_load((const f32x4*)(dis + g)); \
    }

#define STOREA_F(KC) \
    _Pragma("unroll") for (int r = 0; r < AR4; ++r) { \
        int e4 = r * 256 + tid; int row = e4 >> 5; int col = (e4 & 31) * 4; \
        bf16x4 v; \
        _Pragma("unroll") for (int j = 0; j < 4; ++j) v[j] = (short)f2b(rAa[r][j] * rAd[r][j]); \
        if constexpr (MODE == 1) \
            *(bf16x4*)(Abf + (size_t)(i0 + row) * NROWS + (KC) + col) = v; \
        int bo = ((row * BK + col) * 2) ^ ((row & 7) << 4); \
        *(bf16x4*)((char*)As + bo) = v; \
    }

#define LOADB_C(KC) \
    _Pragma("unroll") for (int r = 0; r < BR8; ++r) { \
        int e8 = r * 256 + tid; \
        rB[r] = *(const bf16x8*)(St + (size_t)(e8 >> 4) * NROWS + (KC) + (e8 & 15) * 8); \
    }

#define STOREB_C() \
    _Pragma("unroll") for (int r = 0; r < BR8; ++r) { \
        int e8 = r * 256 + tid; int c = e8 >> 4; int col = (e8 & 15) * 8; \
        int bo = ((c * BK + col) * 2) ^ ((c & 7) << 4); \
        *(bf16x8*)((char*)Bs + bo) = rB[r]; \
    }

#define MFMA_C() \
    _Pragma("unroll") \
    for (int ks = 0; ks < BK; ks += 32) { \
        int ao = ((arow * BK + ks + kb) * 2) ^ ((arow & 7) << 4); \
        bf16x8 af = *(const bf16x8*)((const char*)As + ao); \
        _Pragma("unroll") \
        for (int ct = 0; ct < CT; ++ct) { \
            int bcol = ct * 16 + l15; \
            int bo = ((bcol * BK + ks + kb) * 2) ^ ((bcol & 7) << 4); \
            bf16x8 bf = *(const bf16x8*)((const char*)Bs + bo); \
            acc[ct] = __builtin_amdgcn_mfma_f32_16x16x32_bf16(af, bf, acc[ct], 0, 0, 0); \
        } \
    }

template<int F, int MODE, int KS>
__global__ __launch_bounds__(256) void agg_cold(
    u16* __restrict__ Abf, const float* __restrict__ adj,
    const float* __restrict__ dis, const u16* __restrict__ St,
    u16* __restrict__ Pout) {
    constexpr int CT = F / 16;
    constexpr int BK = 128;
    constexpr int KCH = NROWS / KS;
    constexpr int NCH = KCH / BK;
    constexpr int AR4 = (64 * BK) / (256 * 4);   // 8
    constexpr int BR8 = (F * BK) / (256 * 8);    // 4 (F=64) / 1 (F=16)
    __shared__ __align__(16) u16 As[64 * BK];
    __shared__ __align__(16) u16 Bs[F * BK];
    const int tid  = threadIdx.x;
    const int lane = tid & 63;
    const int wid  = tid >> 6;
    const int i0   = blockIdx.x * 64;
    const int ky   = blockIdx.y;
    const int l15  = lane & 15;
    const int kb   = (lane >> 4) * 8;
    const int k0   = ky * KCH;
    const int arow = wid * 16 + l15;
    f32x4 acc[CT] = {};
    f32x4 rAa[AR4], rAd[AR4];
    bf16x8 rB[BR8];

    LOADA_F(k0)
    LOADB_C(k0)
    for (int ch = 0; ch < NCH; ++ch) {
        const int kc = k0 + ch * BK;
        __syncthreads();
        STOREA_F(kc)
        STOREB_C()
        __syncthreads();
        if (ch + 1 < NCH) { LOADA_F(kc + BK) LOADB_C(kc + BK) }
        MFMA_C()
    }
    u16* P = Pout + (size_t)ky * ((size_t)NROWS * F);
    const int rb = i0 + wid * 16 + (lane >> 4) * 4;
#pragma unroll
    for (int ct = 0; ct < CT; ++ct)
#pragma unroll
        for (int i = 0; i < 4; ++i)
            P[(size_t)(rb + i) * F + ct * 16 + l15] = f2b(acc[ct][i]);
}
#undef LOADA_F
#undef STOREA_F
#undef LOADB_C
#undef STOREB_C
#undef MFMA_C

// ---------------------------------------------------------------------------
// Warm-pass aggregation: A from Abf (L3-resident) via global_load_lds
// width=16, double-buffered, pre-swizzled global source (m173 pattern).
// ---------------------------------------------------------------------------
template<int F>
__global__ __launch_bounds__(256) void agg_warm(
    const u16* __restrict__ Abf, const u16* __restrict__ St,
    u16* __restrict__ Pout) {
    constexpr int CT = F / 16;
    constexpr int BK = 64;
    constexpr int KS = 8;
    constexpr int KCH = NROWS / KS;
    constexpr int NCH = KCH / BK;        // 16
    constexpr int BSLOT = F * BK / 8;
    __shared__ __align__(16) u16 As[2][64 * BK];
    __shared__ __align__(16) u16 Bs[F * BK];
    const int tid  = threadIdx.x;
    const int lane = tid & 63;
    const int wid  = tid >> 6;
    const int i0   = blockIdx.x * 64;
    const int ky   = blockIdx.y;
    const int l15  = lane & 15;
    const int kb   = (lane >> 4) * 8;
    const int k0   = ky * KCH;
    const int arow = wid * 16 + l15;
    f32x4 acc[CT] = {};

    const int arl  = lane >> 3;
    const int agrp = (lane & 7) ^ arl;

#if HAS_GLL
#define ISSUE_A(BUF, KC) \
    _Pragma("unroll") for (int i = 0; i < 2; ++i) { \
        int r0_ = wid * 16 + i * 8; \
        const u16* gp_ = Abf + (size_t)(i0 + r0_ + arl) * NROWS + (KC) + agrp * 8; \
        u16* lp_ = &As[BUF][r0_ * BK]; \
        __builtin_amdgcn_global_load_lds((glb_cvoid*)gp_, (lds_void*)lp_, 16, 0, 0); \
    }
#define STOREA_FB(BUF)
#else
    bf16x8 rA0, rA1;
#define ISSUE_A(BUF, KC) { \
        int e0 = tid, e1 = tid + 256; \
        rA0 = *(const bf16x8*)(Abf + (size_t)(i0 + (e0 >> 3)) * NROWS + (KC) + (((e0 & 7) ^ ((e0 >> 3) & 7)) * 8)); \
        rA1 = *(const bf16x8*)(Abf + (size_t)(i0 + (e1 >> 3)) * NROWS + (KC) + (((e1 & 7) ^ ((e1 >> 3) & 7)) * 8)); \
    }
#define STOREA_FB(BUF) { \
        *(bf16x8*)(&As[BUF][(size_t)tid * 8]) = rA0; \
        *(bf16x8*)(&As[BUF][(size_t)(tid + 256) * 8]) = rA1; \
    }
#endif

    bf16x8 rB0, rB1;
#define LOADB_W(KC) { \
        if constexpr (F == 64) { \
            int c0_ = tid >> 3, g0_ = tid & 7; \
            int c1_ = (tid + 256) >> 3, g1_ = (tid + 256) & 7; \
            rB0 = *(const bf16x8*)(St + (size_t)c0_ * NROWS + (KC) + ((g0_ ^ (c0_ & 7)) * 8)); \
            rB1 = *(const bf16x8*)(St + (size_t)c1_ * NROWS + (KC) + ((g1_ ^ (c1_ & 7)) * 8)); \
        } else { \
            if (tid < BSLOT) { \
                int c0_ = tid >> 3, g0_ = tid & 7; \
                rB0 = *(const bf16x8*)(St + (size_t)c0_ * NROWS + (KC) + ((g0_ ^ (c0_ & 7)) * 8)); \
            } \
        } \
    }
#define STOREB_W() { \
        if constexpr (F == 64) { \
            *(bf16x8*)(&Bs[(size_t)tid * 8]) = rB0; \
            *(bf16x8*)(&Bs[(size_t)(tid + 256) * 8]) = rB1; \
        } else { \
            if (tid < BSLOT) *(bf16x8*)(&Bs[(size_t)tid * 8]) = rB0; \
        } \
    }

    ISSUE_A(0, k0)
    LOADB_W(k0)
    int cur = 0;
    for (int ch = 0; ch < NCH; ++ch) {
        const int kc = k0 + ch * BK;
        __syncthreads();
        STOREB_W()
        STOREA_FB(cur)
        __syncthreads();
        if (ch + 1 < NCH) {
            ISSUE_A(cur ^ 1, kc + BK)
            LOADB_W(kc + BK)
        }
#pragma unroll
        for (int ks = 0; ks < BK; ks += 32) {
            int ao = ((arow * BK + ks + kb) * 2) ^ ((arow & 7) << 4);
            bf16x8 af = *(const bf16x8*)((const char*)As[cur] + ao);
#pragma unroll
            for (int ct = 0; ct < CT; ++ct) {
                int bcol = ct * 16 + l15;
                int bo = ((bcol * BK + ks + kb) * 2) ^ ((bcol & 7) << 4);
                bf16x8 bf = *(const bf16x8*)((const char*)Bs + bo);
                acc[ct] = __builtin_amdgcn_mfma_f32_16x16x32_bf16(af, bf, acc[ct], 0, 0, 0);
            }
        }
        cur ^= 1;
    }
#undef ISSUE_A
#undef STOREA_FB
#undef LOADB_W
#undef STOREB_W
    u16* P = Pout + (size_t)ky * ((size_t)NROWS * F);
    const int rb = i0 + wid * 16 + (lane >> 4) * 4;
#pragma unroll
    for (int ct = 0; ct < CT; ++ct)
#pragma unroll
        for (int i = 0; i < 4; ++i)
            P[(size_t)(rb + i) * F + ct * 16 + l15] = f2b(acc[ct][i]);
}

// ---------------------------------------------------------------------------
// out = sum_{ky} b2f(P[ky]) + bias[col]   (final pass-3 reduce, F=16)
// ---------------------------------------------------------------------------
template<int F, int KS>
__global__ __launch_bounds__(256) void reduce_add(
    const u16* __restrict__ P, const float* __restrict__ bias,
    float* __restrict__ out) {
    constexpr int TOT8 = NROWS * F / 8;
    int i8 = blockIdx.x * 256 + threadIdx.x;
    if (i8 >= TOT8) return;
    constexpr size_t STR = (size_t)NROWS * F;
    float s[8] = {};
#pragma unroll
    for (int k = 0; k < KS; ++k) {
        bf16x8 v = *(const bf16x8*)(P + (size_t)k * STR + (size_t)i8 * 8);
#pragma unroll
        for (int j = 0; j < 8; ++j) s[j] += b2f((u16)v[j]);
    }
    const int c0 = (i8 * 8) % F;
#pragma unroll
    for (int j = 0; j < 8; ++j) s[j] += bias[c0 + j];
    float4* o4 = (float4*)(out + (size_t)i8 * 8);
    float4 oa = {s[0], s[1], s[2], s[3]}, ob = {s[4], s[5], s[6], s[7]};
    o4[0] = oa; o4[1] = ob;
}

extern "C" void kernel_launch(void* const* d_in, const int* in_sizes, int n_in,
                              void* d_out, int out_size, void* d_ws, size_t ws_size,
                              hipStream_t stream) {
    const float* x   = (const float*)d_in[0];
    const float* adj = (const float*)d_in[1];
    const float* dis = (const float*)d_in[2];
    const float* W1  = (const float*)d_in[3];
    const float* b1  = (const float*)d_in[4];
    const float* Wg1 = (const float*)d_in[5];
    const float* bg1 = (const float*)d_in[6];
    const float* Wm1 = (const float*)d_in[7];
    const float* bm1 = (const float*)d_in[8];
    const float* Wm2 = (const float*)d_in[9];
    const float* bm2 = (const float*)d_in[10];
    const float* Wm3 = (const float*)d_in[11];
    const float* bm3 = (const float*)d_in[12];
    const float* Wm4 = (const float*)d_in[13];
    const float* bm4 = (const float*)d_in[14];
    const float* Wgh = (const float*)d_in[15];
    const float* bgh = (const float*)d_in[16];
    const float* W2  = (const float*)d_in[17];
    const float* b2  = (const float*)d_in[18];
    const float* Wg2 = (const float*)d_in[19];
    const float* bg2 = (const float*)d_in[20];
    const float* W3  = (const float*)d_in[21];
    const float* b3  = (const float*)d_in[22];
    float* ws  = (float*)d_ws;
    float* out = (float*)d_out;

    constexpr int KS = 8;
    const size_t ABF_FLOATS = (size_t)NROWS * NROWS / 2;    // bf16 Abf: 128MB
    const size_t P_FLOATS = (size_t)KS * NROWS * 64 / 2;    // bf16 partials (8MB)
    const size_t BASE_FLOATS = 40960 + 262144 + P_FLOATS + 524288;
    const size_t NEED_PRE_BYTES = (ABF_FLOATS + BASE_FLOATS) * 4ULL;  // ~140MB
    const bool pre = ws_size >= NEED_PRE_BYTES;

    float* base = ws + (pre ? ABF_FLOATS : 0);
    float* wsW  = base;                       // fold area: 40960 floats
    float* St_f = wsW + 40960;                // S^T bf16 [64][8192]
    float* P_f  = St_f + 262144;              // partials bf16: KS*8192*64
    float* h4   = P_f + P_FLOATS;             // [8192,64] fp32

    u16* Abf = (u16*)ws;
    u16* St  = (u16*)St_f;
    u16* P   = (u16*)P_f;
    const float* WA = wsW + 0;
    const float* bA = wsW + 8192;
    const float* cA = wsW + 8256;
    const float* WB = wsW + 8320;
    const float* bB = wsW + 9344;
    const float* cB = wsW + 9360;

    fold1<<<18, 256, 0, stream>>>(W1, b1, Wg1, W2, b2, Wg2, wsW);
    fold2<<<10, 256, 0, stream>>>(Wm1, bm1, bg1, W3, b3, bg2, wsW);

    // pass 1 (fused converter): sA^T bf16 ; P = split-K(A @ sA)
    gemm_sA<<<256, 256, 0, stream>>>(x, WA, bA, St);
    if (pre) agg_cold<64, 1, KS><<<dim3(128, KS), 256, 0, stream>>>(Abf, adj, dis, St, P);
    else     agg_cold<64, 2, KS><<<dim3(128, KS), 256, 0, stream>>>(nullptr, adj, dis, St, P);

    // fused reduce1 + med chain: P,cA -> h4 (global) + s2^T (St, bf16)
    med_chain<KS><<<512, 256, 0, stream>>>(P, cA, Wm2, bm2, Wm3, bm3, Wm4, bm4, Wgh, h4, St);

    // pass 2: P = split-K(A @ s2)   (A from L3-warm Abf via global_load_lds)
    if (pre) agg_warm<64><<<dim3(128, KS), 256, 0, stream>>>(Abf, St, P);
    else     agg_cold<64, 2, KS><<<dim3(128, KS), 256, 0, stream>>>(nullptr, adj, dis, St, P);

    // fused reduce2 + sB GEMM
    gemm_sB<KS><<<256, 256, 0, stream>>>(P, bgh, h4, WB, bB, St);

    // pass 3: P = split-K(A @ sB) ; out = sumP + cB
    if (pre) agg_warm<16><<<dim3(128, KS), 256, 0, stream>>>(Abf, St, P);
    else     agg_cold<16, 2, KS><<<dim3(128, KS), 256, 0, stream>>>(nullptr, adj, dis, St, P);
    reduce_add<16, KS><<<64, 256, 0, stream>>>(P, cB, out);
}